// Round 9
// baseline (669.132 us; speedup 1.0000x reference)
//
#include <hip/hip_runtime.h>

#define N_NODES 100000
#define N_EDGES 3200000
#define F_IN 256
#define CH 16
#define FCN 64

#define NPB 64                           // nodes per bucket
#define NBUCK 1563                       // ceil(N_NODES / NPB)
#define NCHUNK 1024                      // edge chunks
#define EPB (N_EDGES / NCHUNK)           // 3125 edges per chunk
#define M (NBUCK * NCHUNK)               // 1600512 scan cells (div by 1024)
#define NSB (M / 1024)                   // 1563 scan blocks
#define ACCP 17                          // padded acc stride (bank spread)

__device__ __forceinline__ unsigned short f2bf(float f) {   // RNE bf16
    unsigned u = __float_as_uint(f);
    unsigned r = (u + 0x7FFFu + ((u >> 16) & 1u)) >> 16;
    return (unsigned short)r;
}

// ---------------- h = x @ w_gcn   [N,256] x [256,16] -> [N,16] (bf16 out: 3.2 MB, L2-resident)
__global__ __launch_bounds__(256) void k_transform(const float* __restrict__ x,
                                                   const float* __restrict__ w,
                                                   unsigned short* __restrict__ h) {
    __shared__ float wlds[CH][F_IN + 4];
    int tid = threadIdx.x;
    for (int i = tid; i < F_IN * CH; i += 256) {
        int k = i >> 4, c = i & 15;
        wlds[c][k] = w[i];
    }
    __syncthreads();
    int c = tid & 15;
    int r = tid >> 4;
    int row = blockIdx.x * 16 + r;
    if (row >= N_NODES) return;
    const float4* xr = reinterpret_cast<const float4*>(x + (size_t)row * F_IN);
    const float4* wr = reinterpret_cast<const float4*>(&wlds[c][0]);
    float acc = 0.f;
    #pragma unroll 8
    for (int k4 = 0; k4 < F_IN / 4; ++k4) {
        float4 xv = xr[k4];
        float4 wv = wr[k4];
        acc = fmaf(xv.x, wv.x, acc);
        acc = fmaf(xv.y, wv.y, acc);
        acc = fmaf(xv.z, wv.z, acc);
        acc = fmaf(xv.w, wv.w, acc);
    }
    h[(size_t)row * CH + c] = f2bf(acc);
}

// ---------------- Phase 1: per-chunk LDS histogram + LDS-atomic rank (1024 blocks)
__global__ __launch_bounds__(256) void k_hist_rank(const int* __restrict__ ei,
                                                   unsigned short* __restrict__ rank16,
                                                   int* __restrict__ histM) {   // [NBUCK][NCHUNK]
    __shared__ int hist[NBUCK];
    int t = threadIdx.x, k = blockIdx.x;
    for (int i = t; i < NBUCK; i += 256) hist[i] = 0;
    __syncthreads();
    int base = k * EPB;
    for (int i = t; i < EPB; i += 256) {
        int e = base + i;
        int dst = ei[N_EDGES + e];
        int r = atomicAdd(&hist[dst >> 6], 1);       // native ds_add_rtn_u32
        rank16[e] = (unsigned short)r;
    }
    __syncthreads();
    for (int i = t; i < NBUCK; i += 256) histM[(size_t)i * NCHUNK + k] = hist[i];
}

// ---------------- Scan pass 1: 1024-cell block sums -> partials[NSB]
__global__ __launch_bounds__(256) void k_scanP1(const int* __restrict__ histM,
                                                int* __restrict__ partials) {
    __shared__ int wsum[4];
    int t = threadIdx.x;
    int4 v = reinterpret_cast<const int4*>(histM)[blockIdx.x * 256 + t];
    int s = v.x + v.y + v.z + v.w;
    #pragma unroll
    for (int off = 32; off > 0; off >>= 1) s += __shfl_xor(s, off, 64);
    if ((t & 63) == 0) wsum[t >> 6] = s;
    __syncthreads();
    if (t == 0) partials[blockIdx.x] = wsum[0] + wsum[1] + wsum[2] + wsum[3];
}

// ---------------- Scan pass 2: exclusive scan of NSB=1563 partials (1 block, 2/thread)
__global__ __launch_bounds__(1024) void k_scanP2(const int* __restrict__ partials,
                                                 int* __restrict__ bases) {
    __shared__ int wsum[16];
    int t = threadIdx.x;
    int i0 = 2 * t, i1 = 2 * t + 1;
    int a = (i0 < NSB) ? partials[i0] : 0;
    int b = (i1 < NSB) ? partials[i1] : 0;
    int s = a + b;
    int lane = t & 63, w = t >> 6;
    int incl = s;
    #pragma unroll
    for (int off = 1; off < 64; off <<= 1) {
        int u = __shfl_up(incl, off, 64);
        if (lane >= off) incl += u;
    }
    if (lane == 63) wsum[w] = incl;
    __syncthreads();
    if (t == 0) {
        int run = 0;
        #pragma unroll
        for (int i = 0; i < 16; ++i) { int u = wsum[i]; wsum[i] = run; run += u; }
    }
    __syncthreads();
    int excl = incl - s + wsum[w];
    if (i0 <= NSB) bases[i0] = excl;
    if (i1 <= NSB) bases[i1] = excl + a;
}

// ---------------- Scan pass 3: local re-scan + base -> offs2d[M+1] (exclusive)
__global__ __launch_bounds__(256) void k_scanP3(const int* __restrict__ histM,
                                                const int* __restrict__ bases,
                                                int* __restrict__ offs2d) {
    __shared__ int wsum[4];
    int t = threadIdx.x;
    int gi = blockIdx.x * 256 + t;
    int4 v = reinterpret_cast<const int4*>(histM)[gi];
    int s = v.x + v.y + v.z + v.w;
    int lane = t & 63, w = t >> 6;
    int incl = s;
    #pragma unroll
    for (int off = 1; off < 64; off <<= 1) {
        int u = __shfl_up(incl, off, 64);
        if (lane >= off) incl += u;
    }
    if (lane == 63) wsum[w] = incl;
    __syncthreads();
    if (t == 0) {
        int a = wsum[0], b = wsum[1], c = wsum[2];
        wsum[0] = 0; wsum[1] = a; wsum[2] = a + b; wsum[3] = a + b + c;
    }
    __syncthreads();
    int excl = incl - s + wsum[w] + bases[blockIdx.x];
    int4 o;
    o.x = excl;
    o.y = excl + v.x;
    o.z = o.y + v.y;
    o.w = o.z + v.z;
    reinterpret_cast<int4*>(offs2d)[gi] = o;
    if (blockIdx.x == 0 && t == 0) offs2d[M] = bases[NSB];
}

// ---------------- Phase 2: deterministic record scatter — zero atomics (1024 blocks)
__global__ __launch_bounds__(256) void k_scatter2(const int* __restrict__ ei,
                                                  const float* __restrict__ ew,
                                                  const unsigned short* __restrict__ rank16,
                                                  const int* __restrict__ offs2d,
                                                  int2* __restrict__ recs) {
    __shared__ int coffs[NBUCK];
    int t = threadIdx.x, k = blockIdx.x;
    for (int i = t; i < NBUCK; i += 256) coffs[i] = offs2d[(size_t)i * NCHUNK + k];
    __syncthreads();
    int base = k * EPB;
    for (int i = t; i < EPB; i += 256) {
        int e = base + i;
        int src = ei[e];
        int dst = ei[N_EDGES + e];
        int b = dst >> 6;
        int local = dst & (NPB - 1);
        int pos = coffs[b] + (int)rank16[e];
        int2 r;
        r.x = src | (local << 17);                 // src < 2^17, local < 2^6
        r.y = __float_as_int(ew[e]);
        recs[pos] = r;
    }
}

// ---------------- Phase 3: bucket aggregation (4 lanes/record, bf16-h gather) + fused head
__global__ __launch_bounds__(256) void k_agg_head(const int2* __restrict__ recs,
                                                  const int* __restrict__ offs2d,
                                                  const unsigned short* __restrict__ h,  // bf16 [N][16]
                                                  const float* __restrict__ w0,  // [16][64]
                                                  const float* __restrict__ b0,  // [64]
                                                  const float* __restrict__ w1,  // [64]
                                                  const float* __restrict__ b1,  // [1]
                                                  float* __restrict__ out) {     // [N]
    __shared__ float acc[NPB * ACCP];    // 4.25 KB, padded stride
    __shared__ float w0s[CH * FCN];      // 4 KB
    __shared__ float w1s[FCN];
    int t = threadIdx.x;
    int b = blockIdx.x;
    for (int i = t; i < NPB * ACCP; i += 256) acc[i] = 0.f;
    for (int i = t; i < CH * FCN; i += 256) w0s[i] = w0[i];
    if (t < FCN) w1s[t] = w1[t];
    __syncthreads();
    int start = offs2d[(size_t)b * NCHUNK];
    int end   = offs2d[(size_t)(b + 1) * NCHUNK];
    int q = t & 3, rs = t >> 2;                    // 64 records in flight per block-iter
    for (int j = start + rs; j < end; j += 64) {
        int2 r = recs[j];                          // 4 lanes broadcast one 8B record
        int src   = r.x & 0x1FFFF;
        int local = r.x >> 17;
        float wv  = __int_as_float(r.y);
        uint2 hv = reinterpret_cast<const uint2*>(h)[src * 4 + q];  // 8B = 4 bf16 (L2-hit)
        float f0 = __uint_as_float(hv.x << 16);
        float f1 = __uint_as_float(hv.x & 0xFFFF0000u);
        float f2 = __uint_as_float(hv.y << 16);
        float f3 = __uint_as_float(hv.y & 0xFFFF0000u);
        float* a = &acc[local * ACCP + q * 4];
        unsafeAtomicAdd(a + 0, f0 * wv);           // ds_add_f32, non-returning
        unsafeAtomicAdd(a + 1, f1 * wv);
        unsafeAtomicAdd(a + 2, f2 * wv);
        unsafeAtomicAdd(a + 3, f3 * wv);
    }
    __syncthreads();
    // head: 4 waves x 16 nodes
    int lane = t & 63, wv4 = t >> 6;
    float bb = b0[lane];
    float w1l = w1s[lane];
    float bias1 = b1[0];
    for (int nl = wv4 * 16; nl < wv4 * 16 + 16; ++nl) {
        int node = b * NPB + nl;
        if (node >= N_NODES) break;
        float o1 = bb;
        #pragma unroll
        for (int kk = 0; kk < CH; ++kk) {
            float a = fmaxf(acc[nl * ACCP + kk], 0.f);   // LDS broadcast
            o1 = fmaf(a, w0s[kk * FCN + lane], o1);
        }
        o1 = fmaxf(o1, 0.f);
        float y = o1 * w1l;
        #pragma unroll
        for (int off = 32; off > 0; off >>= 1) y += __shfl_xor(y, off, 64);
        if (lane == 0) out[node] = y + bias1;
    }
}

// ---------------- Fallback path (ws too small): device atomics, bf16 h
__global__ __launch_bounds__(256) void k_scatter_fb(const int* __restrict__ ei,
                                                    const float* __restrict__ ew,
                                                    const unsigned short* __restrict__ h,
                                                    float* __restrict__ agg) {
    long long t = (long long)blockIdx.x * 256 + threadIdx.x;
    int e = (int)(t >> 2);
    int g = (int)(t & 3);
    if (e >= N_EDGES) return;
    int src = ei[e];
    int dst = ei[N_EDGES + e];
    float w = ew[e];
    uint2 hv = reinterpret_cast<const uint2*>(h)[src * 4 + g];
    float* ap = agg + (size_t)dst * CH + g * 4;
    atomicAdd(ap + 0, __uint_as_float(hv.x << 16) * w);
    atomicAdd(ap + 1, __uint_as_float(hv.x & 0xFFFF0000u) * w);
    atomicAdd(ap + 2, __uint_as_float(hv.y << 16) * w);
    atomicAdd(ap + 3, __uint_as_float(hv.y & 0xFFFF0000u) * w);
}

__global__ __launch_bounds__(256) void k_head_fb(const float* __restrict__ agg,
                                                 const float* __restrict__ w0,
                                                 const float* __restrict__ b0,
                                                 const float* __restrict__ w1,
                                                 const float* __restrict__ b1,
                                                 float* __restrict__ out) {
    __shared__ float w0s[CH * FCN];
    __shared__ float w1s[FCN];
    int tid = threadIdx.x;
    for (int i = tid; i < CH * FCN; i += 256) w0s[i] = w0[i];
    if (tid < FCN) w1s[tid] = w1[tid];
    __syncthreads();
    int lane = tid & 63;
    int wv = tid >> 6;
    int node = blockIdx.x * 4 + wv;
    if (node >= N_NODES) return;
    const float* an = agg + (size_t)node * CH;
    float o1 = b0[lane];
    #pragma unroll
    for (int k = 0; k < CH; ++k) {
        float a = fmaxf(an[k], 0.f);
        o1 = fmaf(a, w0s[k * FCN + lane], o1);
    }
    o1 = fmaxf(o1, 0.f);
    float y = o1 * w1s[lane];
    #pragma unroll
    for (int off = 32; off > 0; off >>= 1) y += __shfl_xor(y, off, 64);
    if (lane == 0) out[node] = y + b1[0];
}

extern "C" void kernel_launch(void* const* d_in, const int* in_sizes, int n_in,
                              void* d_out, int out_size, void* d_ws, size_t ws_size,
                              hipStream_t stream) {
    const float* x  = (const float*)d_in[0];
    const int*   ei = (const int*)  d_in[1];
    const float* ew = (const float*)d_in[2];
    const float* wg = (const float*)d_in[3];
    const float* w0 = (const float*)d_in[4];
    const float* b0 = (const float*)d_in[5];
    const float* w1 = (const float*)d_in[6];
    const float* b1 = (const float*)d_in[7];
    float* out = (float*)d_out;

    // ---- workspace layout (256B-aligned segments) ----
    char* p = (char*)d_ws;
    unsigned short* h = (unsigned short*)p;      p += 3200000;                 // [N][16] bf16
    unsigned short* rank16 = (unsigned short*)p; p += 6400000;                 // [E] u16
    int* histM = (int*)p;                        p += (size_t)M * 4;           // 6.4 MB (256-mult)
    int* offs2d = (int*)p;                       p += 6402304;                 // (M+1)*4 padded
    int* partials = (int*)p;                     p += 6400;                    // NSB ints padded
    int* bases = (int*)p;                        p += 6400;                    // NSB+1 ints padded
    int2* recs = (int2*)p;                       p += (size_t)N_EDGES * 8;     // 25.6 MB
    const size_t need = (size_t)(p - (char*)d_ws);

    if (ws_size >= need) {
        k_transform<<<(N_NODES + 15) / 16, 256, 0, stream>>>(x, wg, h);
        k_hist_rank<<<NCHUNK, 256, 0, stream>>>(ei, rank16, histM);
        k_scanP1<<<NSB, 256, 0, stream>>>(histM, partials);
        k_scanP2<<<1, 1024, 0, stream>>>(partials, bases);
        k_scanP3<<<NSB, 256, 0, stream>>>(histM, bases, offs2d);
        k_scatter2<<<NCHUNK, 256, 0, stream>>>(ei, ew, rank16, offs2d, recs);
        k_agg_head<<<NBUCK, 256, 0, stream>>>(recs, offs2d, h, w0, b0, w1, b1, out);
    } else {
        float* agg = (float*)((char*)d_ws + 3200128);
        hipMemsetAsync(agg, 0, (size_t)N_NODES * CH * 4, stream);
        k_transform<<<(N_NODES + 15) / 16, 256, 0, stream>>>(x, wg, h);
        long long sc_threads = (long long)N_EDGES * 4;
        k_scatter_fb<<<(int)((sc_threads + 255) / 256), 256, 0, stream>>>(ei, ew, h, agg);
        k_head_fb<<<(N_NODES + 3) / 4, 256, 0, stream>>>(agg, w0, b0, w1, b1, out);
    }
}

// Round 10
// 403.405 us; speedup vs baseline: 1.6587x; 1.6587x over previous
//
#include <hip/hip_runtime.h>

#define N_NODES 100000
#define N_EDGES 3200000
#define F_IN 256
#define CH 16
#define FCN 64

#define NPB 64                           // nodes per bucket
#define NBUCK 1563                       // ceil(N_NODES / NPB)
#define NCHUNK 1024                      // edge chunks
#define EPB (N_EDGES / NCHUNK)           // 3125 edges per chunk
#define M (NBUCK * NCHUNK)               // 1600512 scan cells (div by 1024)
#define NSB (M / 1024)                   // 1563 scan blocks
#define ACCP 17                          // padded acc stride (bank spread)
#define CAP 2560                         // sorted-record LDS capacity (mean 2048, sigma 45)

__device__ __forceinline__ unsigned short f2bf(float f) {   // RNE bf16
    unsigned u = __float_as_uint(f);
    unsigned r = (u + 0x7FFFu + ((u >> 16) & 1u)) >> 16;
    return (unsigned short)r;
}

// ---------------- h = x @ w_gcn   [N,256] x [256,16] -> [N,16] (bf16 out: 3.2 MB, L2-resident)
__global__ __launch_bounds__(256) void k_transform(const float* __restrict__ x,
                                                   const float* __restrict__ w,
                                                   unsigned short* __restrict__ h) {
    __shared__ float wlds[CH][F_IN + 4];
    int tid = threadIdx.x;
    for (int i = tid; i < F_IN * CH; i += 256) {
        int k = i >> 4, c = i & 15;
        wlds[c][k] = w[i];
    }
    __syncthreads();
    int c = tid & 15;
    int r = tid >> 4;
    int row = blockIdx.x * 16 + r;
    if (row >= N_NODES) return;
    const float4* xr = reinterpret_cast<const float4*>(x + (size_t)row * F_IN);
    const float4* wr = reinterpret_cast<const float4*>(&wlds[c][0]);
    float acc = 0.f;
    #pragma unroll 8
    for (int k4 = 0; k4 < F_IN / 4; ++k4) {
        float4 xv = xr[k4];
        float4 wv = wr[k4];
        acc = fmaf(xv.x, wv.x, acc);
        acc = fmaf(xv.y, wv.y, acc);
        acc = fmaf(xv.z, wv.z, acc);
        acc = fmaf(xv.w, wv.w, acc);
    }
    h[(size_t)row * CH + c] = f2bf(acc);
}

// ---------------- Phase 1: per-chunk LDS histogram + LDS-atomic rank (1024 blocks)
__global__ __launch_bounds__(256) void k_hist_rank(const int* __restrict__ ei,
                                                   unsigned short* __restrict__ rank16,
                                                   int* __restrict__ histM) {   // [NBUCK][NCHUNK]
    __shared__ int hist[NBUCK];
    int t = threadIdx.x, k = blockIdx.x;
    for (int i = t; i < NBUCK; i += 256) hist[i] = 0;
    __syncthreads();
    int base = k * EPB;
    for (int i = t; i < EPB; i += 256) {
        int e = base + i;
        int dst = ei[N_EDGES + e];
        int r = atomicAdd(&hist[dst >> 6], 1);       // native ds_add_rtn_u32
        rank16[e] = (unsigned short)r;
    }
    __syncthreads();
    for (int i = t; i < NBUCK; i += 256) histM[(size_t)i * NCHUNK + k] = hist[i];
}

// ---------------- Scan pass 1: 1024-cell block sums -> partials[NSB]
__global__ __launch_bounds__(256) void k_scanP1(const int* __restrict__ histM,
                                                int* __restrict__ partials) {
    __shared__ int wsum[4];
    int t = threadIdx.x;
    int4 v = reinterpret_cast<const int4*>(histM)[blockIdx.x * 256 + t];
    int s = v.x + v.y + v.z + v.w;
    #pragma unroll
    for (int off = 32; off > 0; off >>= 1) s += __shfl_xor(s, off, 64);
    if ((t & 63) == 0) wsum[t >> 6] = s;
    __syncthreads();
    if (t == 0) partials[blockIdx.x] = wsum[0] + wsum[1] + wsum[2] + wsum[3];
}

// ---------------- Scan pass 2: exclusive scan of NSB=1563 partials (1 block, 2/thread)
__global__ __launch_bounds__(1024) void k_scanP2(const int* __restrict__ partials,
                                                 int* __restrict__ bases) {
    __shared__ int wsum[16];
    int t = threadIdx.x;
    int i0 = 2 * t, i1 = 2 * t + 1;
    int a = (i0 < NSB) ? partials[i0] : 0;
    int b = (i1 < NSB) ? partials[i1] : 0;
    int s = a + b;
    int lane = t & 63, w = t >> 6;
    int incl = s;
    #pragma unroll
    for (int off = 1; off < 64; off <<= 1) {
        int u = __shfl_up(incl, off, 64);
        if (lane >= off) incl += u;
    }
    if (lane == 63) wsum[w] = incl;
    __syncthreads();
    if (t == 0) {
        int run = 0;
        #pragma unroll
        for (int i = 0; i < 16; ++i) { int u = wsum[i]; wsum[i] = run; run += u; }
    }
    __syncthreads();
    int excl = incl - s + wsum[w];
    if (i0 <= NSB) bases[i0] = excl;
    if (i1 <= NSB) bases[i1] = excl + a;
}

// ---------------- Scan pass 3: local re-scan + base -> offs2d[M+1] (exclusive)
__global__ __launch_bounds__(256) void k_scanP3(const int* __restrict__ histM,
                                                const int* __restrict__ bases,
                                                int* __restrict__ offs2d) {
    __shared__ int wsum[4];
    int t = threadIdx.x;
    int gi = blockIdx.x * 256 + t;
    int4 v = reinterpret_cast<const int4*>(histM)[gi];
    int s = v.x + v.y + v.z + v.w;
    int lane = t & 63, w = t >> 6;
    int incl = s;
    #pragma unroll
    for (int off = 1; off < 64; off <<= 1) {
        int u = __shfl_up(incl, off, 64);
        if (lane >= off) incl += u;
    }
    if (lane == 63) wsum[w] = incl;
    __syncthreads();
    if (t == 0) {
        int a = wsum[0], b = wsum[1], c = wsum[2];
        wsum[0] = 0; wsum[1] = a; wsum[2] = a + b; wsum[3] = a + b + c;
    }
    __syncthreads();
    int excl = incl - s + wsum[w] + bases[blockIdx.x];
    int4 o;
    o.x = excl;
    o.y = excl + v.x;
    o.z = o.y + v.y;
    o.w = o.z + v.z;
    reinterpret_cast<int4*>(offs2d)[gi] = o;
    if (blockIdx.x == 0 && t == 0) offs2d[M] = bases[NSB];
}

// ---------------- Phase 2: deterministic record scatter — zero atomics (1024 blocks)
__global__ __launch_bounds__(256) void k_scatter2(const int* __restrict__ ei,
                                                  const float* __restrict__ ew,
                                                  const unsigned short* __restrict__ rank16,
                                                  const int* __restrict__ offs2d,
                                                  int2* __restrict__ recs) {
    __shared__ int coffs[NBUCK];
    int t = threadIdx.x, k = blockIdx.x;
    for (int i = t; i < NBUCK; i += 256) coffs[i] = offs2d[(size_t)i * NCHUNK + k];
    __syncthreads();
    int base = k * EPB;
    for (int i = t; i < EPB; i += 256) {
        int e = base + i;
        int src = ei[e];
        int dst = ei[N_EDGES + e];
        int b = dst >> 6;
        int local = dst & (NPB - 1);
        int pos = coffs[b] + (int)rank16[e];
        int2 r;
        r.x = src | (local << 17);                 // src < 2^17, local < 2^6
        r.y = __float_as_int(ew[e]);
        recs[pos] = r;
    }
}

// ---------------- Phase 3: in-block counting sort + REGISTER segment-sum + fused head.
// Zero f32 LDS atomics (round-9 invariant suspect). Each thread owns (node, quarter).
__global__ __launch_bounds__(256) void k_agg_head(const int2* __restrict__ recs,
                                                  const int* __restrict__ offs2d,
                                                  const unsigned short* __restrict__ h,  // bf16 [N][16]
                                                  const float* __restrict__ w0,  // [16][64]
                                                  const float* __restrict__ b0,  // [64]
                                                  const float* __restrict__ w1,  // [64]
                                                  const float* __restrict__ b1,  // [1]
                                                  float* __restrict__ out) {     // [N]
    __shared__ int2 sorted[CAP];         // 20 KB node-sorted records
    __shared__ float acc[NPB * ACCP];    // 4.25 KB
    __shared__ float w0s[CH * FCN];      // 4 KB
    __shared__ float w1s[FCN];
    __shared__ int hist64[NPB];
    __shared__ int base64[NPB];
    __shared__ int cur64[NPB];
    int t = threadIdx.x;
    int b = blockIdx.x;
    for (int i = t; i < NPB * ACCP; i += 256) acc[i] = 0.f;
    for (int i = t; i < CH * FCN; i += 256) w0s[i] = w0[i];
    if (t < FCN) w1s[t] = w1[t];
    if (t < NPB) hist64[t] = 0;
    __syncthreads();
    int start = offs2d[(size_t)b * NCHUNK];
    int end   = offs2d[(size_t)(b + 1) * NCHUNK];
    // pass 1: count records per local node (int LDS atomics, native)
    for (int j = start + t; j < end; j += 256) {
        int2 r = recs[j];
        atomicAdd(&hist64[r.x >> 17], 1);
    }
    __syncthreads();
    // 64-lane exclusive scan of hist64 (wave 0)
    if (t < 64) {
        int v = hist64[t];
        int incl = v;
        #pragma unroll
        for (int off = 1; off < 64; off <<= 1) {
            int u = __shfl_up(incl, off, 64);
            if (t >= off) incl += u;
        }
        int excl = incl - v;
        base64[t] = excl;
        cur64[t] = excl;
    }
    __syncthreads();
    // pass 2: place records node-sorted into LDS (recs re-read is L1/L2-hot)
    for (int j = start + t; j < end; j += 256) {
        int2 r = recs[j];
        int nl = r.x >> 17;
        int pos = atomicAdd(&cur64[nl], 1);
        if (pos < CAP) {
            sorted[pos] = r;
        } else {                                    // statistically never (CAP = mean+11σ)
            int src = r.x & 0x1FFFF;
            float wv = __int_as_float(r.y);
            const uint4* hp = reinterpret_cast<const uint4*>(h + (size_t)src * CH);
            uint4 ha = hp[0], hb = hp[1];
            float* a = &acc[nl * ACCP];
            unsafeAtomicAdd(a + 0,  __uint_as_float(ha.x << 16) * wv);
            unsafeAtomicAdd(a + 1,  __uint_as_float(ha.x & 0xFFFF0000u) * wv);
            unsafeAtomicAdd(a + 2,  __uint_as_float(ha.y << 16) * wv);
            unsafeAtomicAdd(a + 3,  __uint_as_float(ha.y & 0xFFFF0000u) * wv);
            unsafeAtomicAdd(a + 4,  __uint_as_float(ha.z << 16) * wv);
            unsafeAtomicAdd(a + 5,  __uint_as_float(ha.z & 0xFFFF0000u) * wv);
            unsafeAtomicAdd(a + 6,  __uint_as_float(ha.w << 16) * wv);
            unsafeAtomicAdd(a + 7,  __uint_as_float(ha.w & 0xFFFF0000u) * wv);
            unsafeAtomicAdd(a + 8,  __uint_as_float(hb.x << 16) * wv);
            unsafeAtomicAdd(a + 9,  __uint_as_float(hb.x & 0xFFFF0000u) * wv);
            unsafeAtomicAdd(a + 10, __uint_as_float(hb.y << 16) * wv);
            unsafeAtomicAdd(a + 11, __uint_as_float(hb.y & 0xFFFF0000u) * wv);
            unsafeAtomicAdd(a + 12, __uint_as_float(hb.z << 16) * wv);
            unsafeAtomicAdd(a + 13, __uint_as_float(hb.z & 0xFFFF0000u) * wv);
            unsafeAtomicAdd(a + 14, __uint_as_float(hb.w << 16) * wv);
            unsafeAtomicAdd(a + 15, __uint_as_float(hb.w & 0xFFFF0000u) * wv);
        }
    }
    __syncthreads();
    // segment sum in REGISTERS: thread (nl, q) owns node nl's channels 4q..4q+3
    int nl = t >> 2, q = t & 3;
    int kb = base64[nl];
    int ke = min(kb + hist64[nl], CAP);
    float a0 = 0.f, a1 = 0.f, a2 = 0.f, a3 = 0.f;
    for (int k = kb; k < ke; ++k) {
        int2 r = sorted[k];                        // 4-lane LDS broadcast
        int src  = r.x & 0x1FFFF;
        float wv = __int_as_float(r.y);
        uint2 hv = reinterpret_cast<const uint2*>(h)[src * 4 + q];  // 16 lines/wave in flight
        a0 = fmaf(__uint_as_float(hv.x << 16),         wv, a0);
        a1 = fmaf(__uint_as_float(hv.x & 0xFFFF0000u), wv, a1);
        a2 = fmaf(__uint_as_float(hv.y << 16),         wv, a2);
        a3 = fmaf(__uint_as_float(hv.y & 0xFFFF0000u), wv, a3);
    }
    float* ap = &acc[nl * ACCP + q * 4];           // owner-exclusive, plain RMW
    ap[0] += a0; ap[1] += a1; ap[2] += a2; ap[3] += a3;
    __syncthreads();
    // head: 4 waves x 16 nodes
    int lane = t & 63, wv4 = t >> 6;
    float bb = b0[lane];
    float w1l = w1s[lane];
    float bias1 = b1[0];
    for (int n2 = wv4 * 16; n2 < wv4 * 16 + 16; ++n2) {
        int node = b * NPB + n2;
        if (node >= N_NODES) break;
        float o1 = bb;
        #pragma unroll
        for (int kk = 0; kk < CH; ++kk) {
            float a = fmaxf(acc[n2 * ACCP + kk], 0.f);   // LDS broadcast
            o1 = fmaf(a, w0s[kk * FCN + lane], o1);
        }
        o1 = fmaxf(o1, 0.f);
        float y = o1 * w1l;
        #pragma unroll
        for (int off = 32; off > 0; off >>= 1) y += __shfl_xor(y, off, 64);
        if (lane == 0) out[node] = y + bias1;
    }
}

// ---------------- Fallback path (ws too small): device atomics, bf16 h
__global__ __launch_bounds__(256) void k_scatter_fb(const int* __restrict__ ei,
                                                    const float* __restrict__ ew,
                                                    const unsigned short* __restrict__ h,
                                                    float* __restrict__ agg) {
    long long t = (long long)blockIdx.x * 256 + threadIdx.x;
    int e = (int)(t >> 2);
    int g = (int)(t & 3);
    if (e >= N_EDGES) return;
    int src = ei[e];
    int dst = ei[N_EDGES + e];
    float w = ew[e];
    uint2 hv = reinterpret_cast<const uint2*>(h)[src * 4 + g];
    float* ap = agg + (size_t)dst * CH + g * 4;
    atomicAdd(ap + 0, __uint_as_float(hv.x << 16) * w);
    atomicAdd(ap + 1, __uint_as_float(hv.x & 0xFFFF0000u) * w);
    atomicAdd(ap + 2, __uint_as_float(hv.y << 16) * w);
    atomicAdd(ap + 3, __uint_as_float(hv.y & 0xFFFF0000u) * w);
}

__global__ __launch_bounds__(256) void k_head_fb(const float* __restrict__ agg,
                                                 const float* __restrict__ w0,
                                                 const float* __restrict__ b0,
                                                 const float* __restrict__ w1,
                                                 const float* __restrict__ b1,
                                                 float* __restrict__ out) {
    __shared__ float w0s[CH * FCN];
    __shared__ float w1s[FCN];
    int tid = threadIdx.x;
    for (int i = tid; i < CH * FCN; i += 256) w0s[i] = w0[i];
    if (tid < FCN) w1s[tid] = w1[tid];
    __syncthreads();
    int lane = tid & 63;
    int wv = tid >> 6;
    int node = blockIdx.x * 4 + wv;
    if (node >= N_NODES) return;
    const float* an = agg + (size_t)node * CH;
    float o1 = b0[lane];
    #pragma unroll
    for (int k = 0; k < CH; ++k) {
        float a = fmaxf(an[k], 0.f);
        o1 = fmaf(a, w0s[k * FCN + lane], o1);
    }
    o1 = fmaxf(o1, 0.f);
    float y = o1 * w1s[lane];
    #pragma unroll
    for (int off = 32; off > 0; off >>= 1) y += __shfl_xor(y, off, 64);
    if (lane == 0) out[node] = y + b1[0];
}

extern "C" void kernel_launch(void* const* d_in, const int* in_sizes, int n_in,
                              void* d_out, int out_size, void* d_ws, size_t ws_size,
                              hipStream_t stream) {
    const float* x  = (const float*)d_in[0];
    const int*   ei = (const int*)  d_in[1];
    const float* ew = (const float*)d_in[2];
    const float* wg = (const float*)d_in[3];
    const float* w0 = (const float*)d_in[4];
    const float* b0 = (const float*)d_in[5];
    const float* w1 = (const float*)d_in[6];
    const float* b1 = (const float*)d_in[7];
    float* out = (float*)d_out;

    // ---- workspace layout (256B-aligned segments) ----
    char* p = (char*)d_ws;
    unsigned short* h = (unsigned short*)p;      p += 3200000;                 // [N][16] bf16
    unsigned short* rank16 = (unsigned short*)p; p += 6400000;                 // [E] u16
    int* histM = (int*)p;                        p += (size_t)M * 4;           // 6.4 MB (256-mult)
    int* offs2d = (int*)p;                       p += 6402304;                 // (M+1)*4 padded
    int* partials = (int*)p;                     p += 6400;                    // NSB ints padded
    int* bases = (int*)p;                        p += 6400;                    // NSB+1 ints padded
    int2* recs = (int2*)p;                       p += (size_t)N_EDGES * 8;     // 25.6 MB
    const size_t need = (size_t)(p - (char*)d_ws);

    if (ws_size >= need) {
        k_transform<<<(N_NODES + 15) / 16, 256, 0, stream>>>(x, wg, h);
        k_hist_rank<<<NCHUNK, 256, 0, stream>>>(ei, rank16, histM);
        k_scanP1<<<NSB, 256, 0, stream>>>(histM, partials);
        k_scanP2<<<1, 1024, 0, stream>>>(partials, bases);
        k_scanP3<<<NSB, 256, 0, stream>>>(histM, bases, offs2d);
        k_scatter2<<<NCHUNK, 256, 0, stream>>>(ei, ew, rank16, offs2d, recs);
        k_agg_head<<<NBUCK, 256, 0, stream>>>(recs, offs2d, h, w0, b0, w1, b1, out);
    } else {
        float* agg = (float*)((char*)d_ws + 3200128);
        hipMemsetAsync(agg, 0, (size_t)N_NODES * CH * 4, stream);
        k_transform<<<(N_NODES + 15) / 16, 256, 0, stream>>>(x, wg, h);
        long long sc_threads = (long long)N_EDGES * 4;
        k_scatter_fb<<<(int)((sc_threads + 255) / 256), 256, 0, stream>>>(ei, ew, h, agg);
        k_head_fb<<<(N_NODES + 3) / 4, 256, 0, stream>>>(agg, w0, b0, w1, b1, out);
    }
}

// Round 11
// 345.368 us; speedup vs baseline: 1.9374x; 1.1680x over previous
//
#include <hip/hip_runtime.h>

#define N_NODES 100000
#define N_EDGES 3200000
#define F_IN 256
#define CH 16
#define FCN 64

#define NPB 64                           // nodes per bucket
#define NBUCK 1563                       // ceil(N_NODES / NPB)
#define NCHUNK 1024                      // edge chunks
#define EPB (N_EDGES / NCHUNK)           // 3125 edges per chunk
#define M (NBUCK * NCHUNK)               // 1600512 scan cells (div by 1024)
#define NSB (M / 1024)                   // 1563 scan blocks
#define ACCP 17                          // padded acc stride (bank spread)
#define CAP 2560                         // sorted-record LDS capacity (mean 2048)
#define TGRID ((N_NODES + 63) / 64)      // 1563 transform blocks (64 rows each)

typedef __attribute__((ext_vector_type(8))) short bf16x8;
typedef __attribute__((ext_vector_type(4))) float f32x4;

__device__ __forceinline__ unsigned short f2bf(float f) {   // RNE bf16
    unsigned u = __float_as_uint(f);
    unsigned r = (u + 0x7FFFu + ((u >> 16) & 1u)) >> 16;
    return (unsigned short)r;
}

// ---------------- h = x @ w_gcn via MFMA bf16.  64 rows/block, 4 waves x 16 rows.
// x staged coalesced (64KB contiguous/block) as swizzled bf16; 8 MFMAs/wave.
__global__ __launch_bounds__(256) void k_transform(const float* __restrict__ x,
                                                   const float* __restrict__ w,
                                                   unsigned short* __restrict__ h) {
    __shared__ unsigned short xs[64 * 256];      // 32 KB bf16, XOR-swizzled rows
    __shared__ unsigned short bs[8 * 64 * 8];    // 8 KB B-fragments
    int t = threadIdx.x;
    int r0 = blockIdx.x * 64;
    // Build B frags once: entry (kk,l): w[kk*32+(l>>4)*8 + j][l&15], j=0..7 (bf16, 16B)
    for (int ei_ = t; ei_ < 512; ei_ += 256) {
        int kk = ei_ >> 6, l = ei_ & 63;
        int c = l & 15, kb = kk * 32 + ((l >> 4) << 3);
        unsigned short tmp[8];
        #pragma unroll
        for (int j = 0; j < 8; ++j) tmp[j] = f2bf(w[(kb + j) * 16 + c]);
        uint4 v;
        v.x = tmp[0] | ((unsigned)tmp[1] << 16);
        v.y = tmp[2] | ((unsigned)tmp[3] << 16);
        v.z = tmp[4] | ((unsigned)tmp[5] << 16);
        v.w = tmp[6] | ((unsigned)tmp[7] << 16);
        *reinterpret_cast<uint4*>(&bs[ei_ * 8]) = v;
    }
    // Stage x: 64 rows x 256 f32 = 4096 float4, fully coalesced; cvt->bf16; swizzle bits 4-6
    #pragma unroll
    for (int i = 0; i < 16; ++i) {
        int f = i * 256 + t;                     // float4 index in tile
        int r = f >> 6, c4 = f & 63;
        int row = r0 + r;
        float4 xv = make_float4(0.f, 0.f, 0.f, 0.f);
        if (row < N_NODES) xv = reinterpret_cast<const float4*>(x)[(size_t)row * 64 + c4];
        unsigned lo = f2bf(xv.x) | ((unsigned)f2bf(xv.y) << 16);
        unsigned hi = f2bf(xv.z) | ((unsigned)f2bf(xv.w) << 16);
        int byte = r * 512 + ((c4 * 8) ^ ((r & 7) << 4));
        *reinterpret_cast<uint2*>(reinterpret_cast<char*>(xs) + byte) = make_uint2(lo, hi);
    }
    __syncthreads();
    int wv = t >> 6, l = t & 63;
    int rl = (wv << 4) + (l & 15);               // A row (local)
    f32x4 acc = {0.f, 0.f, 0.f, 0.f};
    #pragma unroll
    for (int kk = 0; kk < 8; ++kk) {
        int abyte = rl * 512 + (((kk << 6) + ((l >> 4) << 4)) ^ ((rl & 7) << 4));
        bf16x8 av = *reinterpret_cast<const bf16x8*>(reinterpret_cast<const char*>(xs) + abyte);
        bf16x8 bv = *reinterpret_cast<const bf16x8*>(&bs[((kk << 6) + l) * 8]);
        acc = __builtin_amdgcn_mfma_f32_16x16x32_bf16(av, bv, acc, 0, 0, 0);
    }
    // C/D: col = lane&15, row_local = (lane>>4)*4 + j   [guide §3, m89-verified]
    int col = l & 15;
    #pragma unroll
    for (int j = 0; j < 4; ++j) {
        int row = r0 + (wv << 4) + ((l >> 4) << 2) + j;
        if (row < N_NODES) h[(size_t)row * CH + col] = f2bf(acc[j]);
    }
}

// ---------------- Phase 1: per-chunk LDS histogram + LDS-atomic rank (1024 blocks)
__global__ __launch_bounds__(256) void k_hist_rank(const int* __restrict__ ei,
                                                   unsigned short* __restrict__ rank16,
                                                   int* __restrict__ histM) {   // [NBUCK][NCHUNK]
    __shared__ int hist[NBUCK];
    int t = threadIdx.x, k = blockIdx.x;
    for (int i = t; i < NBUCK; i += 256) hist[i] = 0;
    __syncthreads();
    int base = k * EPB;
    for (int i = t; i < EPB; i += 256) {
        int e = base + i;
        int dst = ei[N_EDGES + e];
        int r = atomicAdd(&hist[dst >> 6], 1);       // native ds_add_rtn_u32
        rank16[e] = (unsigned short)r;
    }
    __syncthreads();
    for (int i = t; i < NBUCK; i += 256) histM[(size_t)i * NCHUNK + k] = hist[i];
}

// ---------------- Scan pass 1: 1024-cell block sums -> partials[NSB]
__global__ __launch_bounds__(256) void k_scanP1(const int* __restrict__ histM,
                                                int* __restrict__ partials) {
    __shared__ int wsum[4];
    int t = threadIdx.x;
    int4 v = reinterpret_cast<const int4*>(histM)[blockIdx.x * 256 + t];
    int s = v.x + v.y + v.z + v.w;
    #pragma unroll
    for (int off = 32; off > 0; off >>= 1) s += __shfl_xor(s, off, 64);
    if ((t & 63) == 0) wsum[t >> 6] = s;
    __syncthreads();
    if (t == 0) partials[blockIdx.x] = wsum[0] + wsum[1] + wsum[2] + wsum[3];
}

// ---------------- Scan pass 2: exclusive scan of NSB=1563 partials (1 block, 2/thread)
__global__ __launch_bounds__(1024) void k_scanP2(const int* __restrict__ partials,
                                                 int* __restrict__ bases) {
    __shared__ int wsum[16];
    int t = threadIdx.x;
    int i0 = 2 * t, i1 = 2 * t + 1;
    int a = (i0 < NSB) ? partials[i0] : 0;
    int b = (i1 < NSB) ? partials[i1] : 0;
    int s = a + b;
    int lane = t & 63, w = t >> 6;
    int incl = s;
    #pragma unroll
    for (int off = 1; off < 64; off <<= 1) {
        int u = __shfl_up(incl, off, 64);
        if (lane >= off) incl += u;
    }
    if (lane == 63) wsum[w] = incl;
    __syncthreads();
    if (t == 0) {
        int run = 0;
        #pragma unroll
        for (int i = 0; i < 16; ++i) { int u = wsum[i]; wsum[i] = run; run += u; }
    }
    __syncthreads();
    int excl = incl - s + wsum[w];
    if (i0 <= NSB) bases[i0] = excl;
    if (i1 <= NSB) bases[i1] = excl + a;
}

// ---------------- Scan pass 3: local re-scan + base -> offs2d[M+1] (exclusive)
__global__ __launch_bounds__(256) void k_scanP3(const int* __restrict__ histM,
                                                const int* __restrict__ bases,
                                                int* __restrict__ offs2d) {
    __shared__ int wsum[4];
    int t = threadIdx.x;
    int gi = blockIdx.x * 256 + t;
    int4 v = reinterpret_cast<const int4*>(histM)[gi];
    int s = v.x + v.y + v.z + v.w;
    int lane = t & 63, w = t >> 6;
    int incl = s;
    #pragma unroll
    for (int off = 1; off < 64; off <<= 1) {
        int u = __shfl_up(incl, off, 64);
        if (lane >= off) incl += u;
    }
    if (lane == 63) wsum[w] = incl;
    __syncthreads();
    if (t == 0) {
        int a = wsum[0], b = wsum[1], c = wsum[2];
        wsum[0] = 0; wsum[1] = a; wsum[2] = a + b; wsum[3] = a + b + c;
    }
    __syncthreads();
    int excl = incl - s + wsum[w] + bases[blockIdx.x];
    int4 o;
    o.x = excl;
    o.y = excl + v.x;
    o.z = o.y + v.y;
    o.w = o.z + v.z;
    reinterpret_cast<int4*>(offs2d)[gi] = o;
    if (blockIdx.x == 0 && t == 0) offs2d[M] = bases[NSB];
}

// ---------------- Phase 2: edge-parallel record scatter (12500 blocks, full occupancy)
__global__ __launch_bounds__(256) void k_scatter2(const int* __restrict__ ei,
                                                  const float* __restrict__ ew,
                                                  const unsigned short* __restrict__ rank16,
                                                  const int* __restrict__ offs2d,
                                                  int2* __restrict__ recs) {
    int e = blockIdx.x * 256 + threadIdx.x;
    if (e >= N_EDGES) return;
    int k = e / EPB;                               // chunk id (magic-mul const div)
    int src = ei[e];
    int dst = ei[N_EDGES + e];
    int b = dst >> 6;
    int local = dst & (NPB - 1);
    int pos = offs2d[(size_t)b * NCHUNK + k] + (int)rank16[e];   // L2-resident gather
    int2 r;
    r.x = src | (local << 17);                     // src < 2^17, local < 2^6
    r.y = __float_as_int(ew[e]);
    recs[pos] = r;
}

// ---------------- Phase 3: in-block counting sort + REGISTER segment-sum + fused head.
__global__ __launch_bounds__(256) void k_agg_head(const int2* __restrict__ recs,
                                                  const int* __restrict__ offs2d,
                                                  const unsigned short* __restrict__ h,  // bf16 [N][16]
                                                  const float* __restrict__ w0,  // [16][64]
                                                  const float* __restrict__ b0,  // [64]
                                                  const float* __restrict__ w1,  // [64]
                                                  const float* __restrict__ b1,  // [1]
                                                  float* __restrict__ out) {     // [N]
    __shared__ int2 sorted[CAP];         // 20 KB node-sorted records
    __shared__ float acc[NPB * ACCP];    // 4.25 KB
    __shared__ float w0s[CH * FCN];      // 4 KB
    __shared__ float w1s[FCN];
    __shared__ int hist64[NPB];
    __shared__ int base64[NPB];
    __shared__ int cur64[NPB];
    int t = threadIdx.x;
    int b = blockIdx.x;
    for (int i = t; i < NPB * ACCP; i += 256) acc[i] = 0.f;
    for (int i = t; i < CH * FCN; i += 256) w0s[i] = w0[i];
    if (t < FCN) w1s[t] = w1[t];
    if (t < NPB) hist64[t] = 0;
    __syncthreads();
    int start = offs2d[(size_t)b * NCHUNK];
    int end   = offs2d[(size_t)(b + 1) * NCHUNK];
    for (int j = start + t; j < end; j += 256) {
        int2 r = recs[j];
        atomicAdd(&hist64[r.x >> 17], 1);
    }
    __syncthreads();
    if (t < 64) {
        int v = hist64[t];
        int incl = v;
        #pragma unroll
        for (int off = 1; off < 64; off <<= 1) {
            int u = __shfl_up(incl, off, 64);
            if (t >= off) incl += u;
        }
        int excl = incl - v;
        base64[t] = excl;
        cur64[t] = excl;
    }
    __syncthreads();
    for (int j = start + t; j < end; j += 256) {
        int2 r = recs[j];
        int nl = r.x >> 17;
        int pos = atomicAdd(&cur64[nl], 1);
        if (pos < CAP) {
            sorted[pos] = r;
        } else {                                    // statistically never
            int src = r.x & 0x1FFFF;
            float wv = __int_as_float(r.y);
            const uint4* hp = reinterpret_cast<const uint4*>(h + (size_t)src * CH);
            uint4 ha = hp[0], hb = hp[1];
            float* a = &acc[nl * ACCP];
            unsafeAtomicAdd(a + 0,  __uint_as_float(ha.x << 16) * wv);
            unsafeAtomicAdd(a + 1,  __uint_as_float(ha.x & 0xFFFF0000u) * wv);
            unsafeAtomicAdd(a + 2,  __uint_as_float(ha.y << 16) * wv);
            unsafeAtomicAdd(a + 3,  __uint_as_float(ha.y & 0xFFFF0000u) * wv);
            unsafeAtomicAdd(a + 4,  __uint_as_float(ha.z << 16) * wv);
            unsafeAtomicAdd(a + 5,  __uint_as_float(ha.z & 0xFFFF0000u) * wv);
            unsafeAtomicAdd(a + 6,  __uint_as_float(ha.w << 16) * wv);
            unsafeAtomicAdd(a + 7,  __uint_as_float(ha.w & 0xFFFF0000u) * wv);
            unsafeAtomicAdd(a + 8,  __uint_as_float(hb.x << 16) * wv);
            unsafeAtomicAdd(a + 9,  __uint_as_float(hb.x & 0xFFFF0000u) * wv);
            unsafeAtomicAdd(a + 10, __uint_as_float(hb.y << 16) * wv);
            unsafeAtomicAdd(a + 11, __uint_as_float(hb.y & 0xFFFF0000u) * wv);
            unsafeAtomicAdd(a + 12, __uint_as_float(hb.z << 16) * wv);
            unsafeAtomicAdd(a + 13, __uint_as_float(hb.z & 0xFFFF0000u) * wv);
            unsafeAtomicAdd(a + 14, __uint_as_float(hb.w << 16) * wv);
            unsafeAtomicAdd(a + 15, __uint_as_float(hb.w & 0xFFFF0000u) * wv);
        }
    }
    __syncthreads();
    // segment sum in REGISTERS: thread (nl, q) owns node nl's channels 4q..4q+3
    int nl = t >> 2, q = t & 3;
    int kb = base64[nl];
    int ke = min(kb + hist64[nl], CAP);
    float a0 = 0.f, a1 = 0.f, a2 = 0.f, a3 = 0.f;
    for (int k = kb; k < ke; ++k) {
        int2 r = sorted[k];                        // 4-lane LDS broadcast
        int src  = r.x & 0x1FFFF;
        float wv = __int_as_float(r.y);
        uint2 hv = reinterpret_cast<const uint2*>(h)[src * 4 + q];
        a0 = fmaf(__uint_as_float(hv.x << 16),         wv, a0);
        a1 = fmaf(__uint_as_float(hv.x & 0xFFFF0000u), wv, a1);
        a2 = fmaf(__uint_as_float(hv.y << 16),         wv, a2);
        a3 = fmaf(__uint_as_float(hv.y & 0xFFFF0000u), wv, a3);
    }
    float* ap = &acc[nl * ACCP + q * 4];
    ap[0] += a0; ap[1] += a1; ap[2] += a2; ap[3] += a3;
    __syncthreads();
    // head: 4 waves x 16 nodes
    int lane = t & 63, wv4 = t >> 6;
    float bb = b0[lane];
    float w1l = w1s[lane];
    float bias1 = b1[0];
    for (int n2 = wv4 * 16; n2 < wv4 * 16 + 16; ++n2) {
        int node = b * NPB + n2;
        if (node >= N_NODES) break;
        float o1 = bb;
        #pragma unroll
        for (int kk = 0; kk < CH; ++kk) {
            float a = fmaxf(acc[n2 * ACCP + kk], 0.f);
            o1 = fmaf(a, w0s[kk * FCN + lane], o1);
        }
        o1 = fmaxf(o1, 0.f);
        float y = o1 * w1l;
        #pragma unroll
        for (int off = 32; off > 0; off >>= 1) y += __shfl_xor(y, off, 64);
        if (lane == 0) out[node] = y + bias1;
    }
}

// ---------------- Fallback path (ws too small): device atomics, bf16 h
__global__ __launch_bounds__(256) void k_scatter_fb(const int* __restrict__ ei,
                                                    const float* __restrict__ ew,
                                                    const unsigned short* __restrict__ h,
                                                    float* __restrict__ agg) {
    long long t = (long long)blockIdx.x * 256 + threadIdx.x;
    int e = (int)(t >> 2);
    int g = (int)(t & 3);
    if (e >= N_EDGES) return;
    int src = ei[e];
    int dst = ei[N_EDGES + e];
    float w = ew[e];
    uint2 hv = reinterpret_cast<const uint2*>(h)[src * 4 + g];
    float* ap = agg + (size_t)dst * CH + g * 4;
    atomicAdd(ap + 0, __uint_as_float(hv.x << 16) * w);
    atomicAdd(ap + 1, __uint_as_float(hv.x & 0xFFFF0000u) * w);
    atomicAdd(ap + 2, __uint_as_float(hv.y << 16) * w);
    atomicAdd(ap + 3, __uint_as_float(hv.y & 0xFFFF0000u) * w);
}

__global__ __launch_bounds__(256) void k_head_fb(const float* __restrict__ agg,
                                                 const float* __restrict__ w0,
                                                 const float* __restrict__ b0,
                                                 const float* __restrict__ w1,
                                                 const float* __restrict__ b1,
                                                 float* __restrict__ out) {
    __shared__ float w0s[CH * FCN];
    __shared__ float w1s[FCN];
    int tid = threadIdx.x;
    for (int i = tid; i < CH * FCN; i += 256) w0s[i] = w0[i];
    if (tid < FCN) w1s[tid] = w1[tid];
    __syncthreads();
    int lane = tid & 63;
    int wv = tid >> 6;
    int node = blockIdx.x * 4 + wv;
    if (node >= N_NODES) return;
    const float* an = agg + (size_t)node * CH;
    float o1 = b0[lane];
    #pragma unroll
    for (int k = 0; k < CH; ++k) {
        float a = fmaxf(an[k], 0.f);
        o1 = fmaf(a, w0s[k * FCN + lane], o1);
    }
    o1 = fmaxf(o1, 0.f);
    float y = o1 * w1s[lane];
    #pragma unroll
    for (int off = 32; off > 0; off >>= 1) y += __shfl_xor(y, off, 64);
    if (lane == 0) out[node] = y + b1[0];
}

extern "C" void kernel_launch(void* const* d_in, const int* in_sizes, int n_in,
                              void* d_out, int out_size, void* d_ws, size_t ws_size,
                              hipStream_t stream) {
    const float* x  = (const float*)d_in[0];
    const int*   ei = (const int*)  d_in[1];
    const float* ew = (const float*)d_in[2];
    const float* wg = (const float*)d_in[3];
    const float* w0 = (const float*)d_in[4];
    const float* b0 = (const float*)d_in[5];
    const float* w1 = (const float*)d_in[6];
    const float* b1 = (const float*)d_in[7];
    float* out = (float*)d_out;

    // ---- workspace layout (256B-aligned segments) ----
    char* p = (char*)d_ws;
    unsigned short* h = (unsigned short*)p;      p += 3200000;                 // [N][16] bf16
    unsigned short* rank16 = (unsigned short*)p; p += 6400000;                 // [E] u16
    int* histM = (int*)p;                        p += (size_t)M * 4;           // 6.4 MB
    int* offs2d = (int*)p;                       p += 6402304;                 // (M+1)*4 padded
    int* partials = (int*)p;                     p += 6400;                    // NSB ints padded
    int* bases = (int*)p;                        p += 6400;                    // NSB+1 ints padded
    int2* recs = (int2*)p;                       p += (size_t)N_EDGES * 8;     // 25.6 MB
    const size_t need = (size_t)(p - (char*)d_ws);

    if (ws_size >= need) {
        k_transform<<<TGRID, 256, 0, stream>>>(x, wg, h);
        k_hist_rank<<<NCHUNK, 256, 0, stream>>>(ei, rank16, histM);
        k_scanP1<<<NSB, 256, 0, stream>>>(histM, partials);
        k_scanP2<<<1, 1024, 0, stream>>>(partials, bases);
        k_scanP3<<<NSB, 256, 0, stream>>>(histM, bases, offs2d);
        k_scatter2<<<(N_EDGES + 255) / 256, 256, 0, stream>>>(ei, ew, rank16, offs2d, recs);
        k_agg_head<<<NBUCK, 256, 0, stream>>>(recs, offs2d, h, w0, b0, w1, b1, out);
    } else {
        float* agg = (float*)((char*)d_ws + 3200128);
        hipMemsetAsync(agg, 0, (size_t)N_NODES * CH * 4, stream);
        k_transform<<<TGRID, 256, 0, stream>>>(x, wg, h);
        long long sc_threads = (long long)N_EDGES * 4;
        k_scatter_fb<<<(int)((sc_threads + 255) / 256), 256, 0, stream>>>(ei, ew, h, agg);
        k_head_fb<<<(N_NODES + 3) / 4, 256, 0, stream>>>(agg, w0, b0, w1, b1, out);
    }
}